// Round 1
// baseline (191.520 us; speedup 1.0000x reference)
//
#include <hip/hip_runtime.h>
#include <cstddef>

#define NUM_TYPES    4
#define NUM_SPLINES  16
#define NUM_CHANNELS 64
#define WCOUNT       (16 * NUM_SPLINES * NUM_CHANNELS)   // 16384 floats = 64 KB

// cos(pi/2 * u) via hardware v_cos (input in revolutions: cos(2*pi*r)).
// Here |u| <= ~1.9 so |u/4| < 0.5 -> no range reduction needed.
__device__ __forceinline__ float cospi_half(float u) {
    float r;
    asm("v_cos_f32 %0, %1" : "=v"(r) : "v"(u * 0.25f));
    return r;
}

__global__ __launch_bounds__(512, 2)
void spline_embed_kernel(const int* __restrict__ atom_types,
                         const int* __restrict__ edge_src,
                         const int* __restrict__ edge_dst,
                         const float* __restrict__ norm_length,
                         const float* __restrict__ class_weight,
                         float* __restrict__ out,
                         int n_edges)
{
    __shared__ __align__(16) float lds_w[WCOUNT];   // 64 KB: [class][spline][channel]

    // ---- stage class weights global -> LDS (coalesced float4) ----
    {
        const float4* src = reinterpret_cast<const float4*>(class_weight);
        float4*       dst = reinterpret_cast<float4*>(lds_w);
        for (int i = threadIdx.x; i < WCOUNT / 4; i += blockDim.x)
            dst[i] = src[i];
    }
    __syncthreads();

    const int lane = threadIdx.x & 63;
    const int g    = lane >> 4;          // 16-lane group 0..3 (edge within step)
    const int c0   = (lane & 15) << 2;   // this lane's first channel (4 channels)

    const int waves_per_block = blockDim.x >> 6;
    const int gwave  = blockIdx.x * waves_per_block + (threadIdx.x >> 6);
    const int nwaves = gridDim.x * waves_per_block;

    const int nchunks = (n_edges + 63) >> 6;   // 64 edges per wave-chunk

    for (int chunk = gwave; chunk < nchunks; chunk += nwaves) {
        const int e0 = chunk << 6;

        // ---- coalesced metadata load: lane handles edge e0+lane ----
        int   et_m = 0;
        float t_m  = 0.0f;
        {
            const int em = e0 + lane;
            if (em < n_edges) {
                const int i0 = edge_src[em];
                const int i1 = edge_dst[em];
                et_m = atom_types[i0] * NUM_TYPES + atom_types[i1];
                t_m  = norm_length[em] * 15.0f;   // t = x/h, h = 1/15
            }
        }

        // ---- 16 steps x 4 edges: group g does edge e0 + 4k + g ----
        #pragma unroll 2
        for (int k = 0; k < 16; ++k) {
            const int idx  = (k << 2) + g;          // edge index within chunk
            const int e    = e0 + idx;
            const int et_e = __shfl(et_m, idx);
            const float t  = __shfl(t_m, idx);

            // active spline window: s in (t-6, t+6) -> 12 ints from (int)t - 5
            int slo = (int)t - 5;
            slo = slo < 0 ? 0 : slo;

            const float* wb = &lds_w[(et_e << 10) + c0];

            float ax = 0.0f, ay = 0.0f, az = 0.0f, aw = 0.0f;
            #pragma unroll
            for (int i = 0; i < 12; ++i) {
                const int   s = slo + i;
                const float u = (t - (float)s) * (1.0f / 6.0f);
                const float c = cospi_half(u);
                float b = c * c;
                b = (fabsf(u) < 1.0f && s < NUM_SPLINES) ? b : 0.0f;
                const float4 w = *reinterpret_cast<const float4*>(&wb[(s & 15) << 6]);
                ax = fmaf(b, w.x, ax);
                ay = fmaf(b, w.y, ay);
                az = fmaf(b, w.z, az);
                aw = fmaf(b, w.w, aw);
            }

            if (e < n_edges) {
                float4 o = {ax, ay, az, aw};
                *reinterpret_cast<float4*>(&out[(size_t)e * NUM_CHANNELS + c0]) = o;
            }
        }
    }
}

extern "C" void kernel_launch(void* const* d_in, const int* in_sizes, int n_in,
                              void* d_out, int out_size, void* d_ws, size_t ws_size,
                              hipStream_t stream)
{
    const int*   atom_types   = (const int*)d_in[0];
    const int*   edge_index   = (const int*)d_in[1];
    const float* norm_length  = (const float*)d_in[2];
    const float* class_weight = (const float*)d_in[3];
    float*       out          = (float*)d_out;

    const int n_edges  = in_sizes[2];            // |norm_length| = E
    const int* edge_src = edge_index;            // row 0 of [2, E]
    const int* edge_dst = edge_index + n_edges;  // row 1

    dim3 block(512);
    dim3 grid(1024);
    hipLaunchKernelGGL(spline_embed_kernel, grid, block, 0, stream,
                       atom_types, edge_src, edge_dst, norm_length,
                       class_weight, out, n_edges);
}

// Round 2
// 186.069 us; speedup vs baseline: 1.0293x; 1.0293x over previous
//
#include <hip/hip_runtime.h>
#include <cstddef>

#define NUM_TYPES    4
#define NUM_SPLINES  16
#define NUM_CHANNELS 64
#define WFLOATS      (16 * NUM_SPLINES * NUM_CHANNELS)     // 16384 f32
#define WU32         (WFLOATS / 2)                          // 8192 u32 (bf16x2) = 32 KB

// cos(pi/2 * u) where u4 = u/4, via hardware v_cos (input in revolutions).
// |u4| < 0.5 always here -> no range reduction needed.
__device__ __forceinline__ float cos_rev(float u4) {
    float r;
    asm("v_cos_f32 %0, %1" : "=v"(r) : "v"(u4));
    return r;
}

// round-to-nearest-even f32 -> bf16, packed pair (a=low16, b=high16)
__device__ __forceinline__ unsigned pack_bf16(float a, float b) {
    unsigned ua = __float_as_uint(a);
    unsigned ub = __float_as_uint(b);
    ua += 0x7fffu + ((ua >> 16) & 1u);
    ub += 0x7fffu + ((ub >> 16) & 1u);
    return (ua >> 16) | (ub & 0xffff0000u);
}

__device__ __forceinline__ float bf_lo(unsigned w) { return __uint_as_float(w << 16); }
__device__ __forceinline__ float bf_hi(unsigned w) { return __uint_as_float(w & 0xffff0000u); }

__global__ __launch_bounds__(512, 4)
void spline_embed_kernel(const int* __restrict__ atom_types,
                         const int* __restrict__ edge_src,
                         const int* __restrict__ edge_dst,
                         const float* __restrict__ norm_length,
                         const float* __restrict__ class_weight,
                         float* __restrict__ out,
                         int n_edges)
{
    // [class][spline][64ch as 32 x bf16x2] = 32 KB
    __shared__ __align__(16) unsigned lds_w[WU32];

    // ---- stage weights global(f32) -> LDS(bf16x2), coalesced ----
    {
        const float2* src = reinterpret_cast<const float2*>(class_weight);
        for (int i = threadIdx.x; i < WU32; i += blockDim.x) {
            float2 v = src[i];
            lds_w[i] = pack_bf16(v.x, v.y);
        }
    }
    __syncthreads();

    const int lane = threadIdx.x & 63;
    const int g    = lane >> 3;          // 8-lane group 0..7 (edge within step)
    const int cl   = lane & 7;           // channel octet: channels cl*8 .. cl*8+7

    const int waves_per_block = blockDim.x >> 6;
    const int gwave  = blockIdx.x * waves_per_block + (threadIdx.x >> 6);
    const int nwaves = gridDim.x * waves_per_block;

    const int nchunks = (n_edges + 63) >> 6;   // 64 edges per wave-chunk

    for (int chunk = gwave; chunk < nchunks; chunk += nwaves) {
        const int e0 = chunk << 6;

        // ---- coalesced metadata load: lane handles edge e0+lane ----
        int   et_m = 0;
        float t_m  = 0.0f;
        {
            const int em = e0 + lane;
            if (em < n_edges) {
                const int i0 = edge_src[em];
                const int i1 = edge_dst[em];
                et_m = atom_types[i0] * NUM_TYPES + atom_types[i1];
                t_m  = norm_length[em] * 15.0f;   // t = x/h, h = 1/15
            }
        }

        // ---- 8 steps x 8 edges: group g does edge e0 + 8k + g ----
        #pragma unroll 2
        for (int k = 0; k < 8; ++k) {
            const int idx  = (k << 3) + g;          // edge index within chunk
            const int e    = e0 + idx;
            const int et_e = __shfl(et_m, idx);
            const float t  = __shfl(t_m, idx);

            // active window: 12 splines from slo; clamp so slo+11 <= 15.
            int slo = (int)t - 5;
            slo = slo < 0 ? 0 : (slo > 4 ? 4 : slo);

            // u4_i = (t - (slo+i)) / 24 ; basis = cos^2(2*pi*u4) for |u4|<0.25
            const float bu = (t - (float)slo) * (1.0f / 24.0f);

            // u32 index: class*512 + spline*32 + cl*4
            const unsigned* wb = &lds_w[(et_e << 9) + (slo << 5) + (cl << 2)];

            float a0 = 0.f, a1 = 0.f, a2 = 0.f, a3 = 0.f;
            float a4 = 0.f, a5 = 0.f, a6 = 0.f, a7 = 0.f;
            #pragma unroll
            for (int i = 0; i < 12; ++i) {
                const float u4 = bu - (float)i * (1.0f / 24.0f);
                const float c  = cos_rev(u4);
                const float b  = (fabsf(u4) < 0.25f) ? c * c : 0.0f;
                const uint4 w  = *reinterpret_cast<const uint4*>(wb + (i << 5));
                a0 = fmaf(b, bf_lo(w.x), a0);
                a1 = fmaf(b, bf_hi(w.x), a1);
                a2 = fmaf(b, bf_lo(w.y), a2);
                a3 = fmaf(b, bf_hi(w.y), a3);
                a4 = fmaf(b, bf_lo(w.z), a4);
                a5 = fmaf(b, bf_hi(w.z), a5);
                a6 = fmaf(b, bf_lo(w.w), a6);
                a7 = fmaf(b, bf_hi(w.w), a7);
            }

            if (e < n_edges) {
                float* po = out + (size_t)e * NUM_CHANNELS + (cl << 3);
                float4 o0 = {a0, a1, a2, a3};
                float4 o1 = {a4, a5, a6, a7};
                *reinterpret_cast<float4*>(po)     = o0;
                *reinterpret_cast<float4*>(po + 4) = o1;
            }
        }
    }
}

extern "C" void kernel_launch(void* const* d_in, const int* in_sizes, int n_in,
                              void* d_out, int out_size, void* d_ws, size_t ws_size,
                              hipStream_t stream)
{
    const int*   atom_types   = (const int*)d_in[0];
    const int*   edge_index   = (const int*)d_in[1];
    const float* norm_length  = (const float*)d_in[2];
    const float* class_weight = (const float*)d_in[3];
    float*       out          = (float*)d_out;

    const int n_edges  = in_sizes[2];            // |norm_length| = E
    const int* edge_src = edge_index;            // row 0 of [2, E]
    const int* edge_dst = edge_index + n_edges;  // row 1

    dim3 block(512);
    dim3 grid(1024);
    hipLaunchKernelGGL(spline_embed_kernel, grid, block, 0, stream,
                       atom_types, edge_src, edge_dst, norm_length,
                       class_weight, out, n_edges);
}